// Round 15
// baseline (464.108 us; speedup 1.0000x reference)
//
#include <hip/hip_runtime.h>

// ---- problem constants ----
#define Hdim   3584
#define NH     28
#define NKV    4
#define HD     128
#define Sq     2048
#define NQKV   4608          // 3584 q + 512 k + 512 v
#define KD     3584          // inner dim of both GEMMs

typedef unsigned short u16;
typedef unsigned int   u32;
typedef _Float16 f16;
typedef _Float16 f16x8 __attribute__((ext_vector_type(8)));     // MFMA A/B operand (4 VGPRs)
typedef unsigned short u16x8 __attribute__((ext_vector_type(8)));
typedef float f32x4 __attribute__((ext_vector_type(4)));        // MFMA C/D operand

__device__ __forceinline__ u16 f2h(float x) { f16 h = (f16)x; return __builtin_bit_cast(u16, h); }
__device__ __forceinline__ float h2f(u16 b) { return (float)__builtin_bit_cast(f16, b); }
__device__ __forceinline__ void split2(float x, u16& hi, u16& lo) {
    hi = f2h(x);
    lo = f2h(x - h2f(hi));   // combined ~22-bit mantissa
}

// async global->LDS, 16B per lane; LDS dest = wave-uniform base + lane*16
#define GLL16(gp, lp) __builtin_amdgcn_global_load_lds( \
    (__attribute__((address_space(1))) void*)(gp),      \
    (__attribute__((address_space(3))) void*)(lp), 16, 0, 0)

// ---- AWQ dequant tile body (R7-verified): 64x64 tile via coalesced LDS ----
__device__ __forceinline__ void deq_tile(const int* __restrict__ qw,
                                         const int* __restrict__ qz,
                                         const float* __restrict__ sc,
                                         u16* __restrict__ W, int dout,
                                         int bx, int by, int tid,
                                         u32 (*L)[9], float* scl, u32* zq) {
    int w8 = dout >> 3;
    int c0 = bx * 64, j0 = bx * 8;
    int r0 = by * 64, g = r0 >> 7;               // G=128 -> uniform per tile
#pragma unroll
    for (int t = 0; t < 2; ++t) {
        int u = tid + t * 256;
        int rr = u >> 3, jj = u & 7;             // coalesced: 8 consecutive words/row
        L[rr][jj] = (u32)qw[(size_t)(r0 + rr) * w8 + j0 + jj];
    }
    if (tid < 64) scl[tid] = sc[(size_t)g * dout + c0 + tid];
    if (tid < 8)  zq[tid]  = (u32)qz[(size_t)g * w8 + j0 + tid];
    __syncthreads();
#pragma unroll
    for (int t = 0; t < 2; ++t) {
        int u = tid + t * 256;
        int lc = u >> 3, r8 = (u & 7) << 3;      // chunk: col c0+lc, rows r0+r8..+7
        int sh = (lc & 7) << 2, jc = lc >> 3;
        int z = (int)((zq[jc] >> sh) & 15u);
        float s = scl[lc];
        u16x8 v;
#pragma unroll
        for (int i = 0; i < 8; ++i) {
            int w = (int)((L[r8 + i][jc] >> sh) & 15u);
            v[i] = f2h((float)(w - z) * s);
        }
        *(u16x8*)(W + (size_t)(c0 + lc) * KD + r0 + r8) = v;
    }
}

// ---- fused preprocessing: cvt | bias | deq_q | deq_k | deq_v | [deq_o] ----
// R11-verified. deq_o writes Wo2 (separate buffer, safe before GEMM1).
__global__ __launch_bounds__(256) void k_pre(const float* __restrict__ hidden,
                                             u16* __restrict__ Xh,
                                             const float* __restrict__ bq,
                                             const float* __restrict__ bk,
                                             const float* __restrict__ bv,
                                             float* __restrict__ biasc,
                                             const int* qwq, const int* qzq, const float* scq,
                                             const int* qwk, const int* qzk, const float* sck,
                                             const int* qwv, const int* qzv, const float* scv,
                                             const int* qwo, const int* qzo, const float* sco,
                                             u16* __restrict__ Wh,
                                             u16* __restrict__ Wo2) {
    __shared__ u32 L[64][9];
    __shared__ float scl[64];
    __shared__ u32 zq[8];
    int b = blockIdx.x, tid = threadIdx.x;
    if (b < 3584) {                              // fp32 -> fp16, 8 elems/thread
        int i = b * 256 + tid;
        const float4* p = (const float4*)(hidden + (size_t)i * 8);
        float4 a = p[0], c = p[1];
        float v[8] = {a.x, a.y, a.z, a.w, c.x, c.y, c.z, c.w};
        u16x8 h;
#pragma unroll
        for (int j = 0; j < 8; ++j) h[j] = f2h(v[j]);
        *(u16x8*)(Xh + (size_t)i * 8) = h;
        return;
    }
    b -= 3584;
    if (b < 18) {                                // concat biases (q|k|v)
        int i = b * 256 + tid;
        if (i < NQKV)
            biasc[i] = (i < 3584) ? bq[i] : (i < 4096 ? bk[i - 3584] : bv[i - 4096]);
        return;
    }
    b -= 18;
    if (b < 3136) { deq_tile(qwq, qzq, scq, Wh, 3584, b % 56, b / 56, tid, L, scl, zq); return; }
    b -= 3136;
    if (b < 448)  { deq_tile(qwk, qzk, sck, Wh + (size_t)3584 * KD, 512, b % 8, b / 8, tid, L, scl, zq); return; }
    b -= 448;
    if (b < 448)  { deq_tile(qwv, qzv, scv, Wh + (size_t)4096 * KD, 512, b % 8, b / 8, tid, L, scl, zq); return; }
    b -= 448;
    deq_tile(qwo, qzo, sco, Wo2, 3584, b % 56, b / 56, tid, L, scl, zq);
}

// ---- standalone dequant (fallback when Wo2 doesn't fit the workspace) ----
__global__ __launch_bounds__(256) void k_dequant(const int* __restrict__ qw,
                                                 const int* __restrict__ qz,
                                                 const float* __restrict__ sc,
                                                 u16* __restrict__ W, int dout) {
    __shared__ u32 L[64][9];
    __shared__ float scl[64];
    __shared__ u32 zq[8];
    deq_tile(qw, qz, sc, W, dout, blockIdx.x, blockIdx.y, threadIdx.x, L, scl, zq);
}

// ---- fp16 MFMA GEMM 128x128 (m97-style + T2 XOR-swizzle) ----
// GEMM1's config: 1152 blocks z=2 = 4.5/CU -> 550 TF, best of all structures
// tried for this shape (block-level MLP beats 1-block/CU pipeline depth).
// T2: chunk16B ^= row&7 on BOTH sides; measured conflicts = 0 (R4).
// R6: keep LINEAR block order (XCD chunking thrashed L3, FETCH +48%).
__global__ __launch_bounds__(256) void k_gemm_f16(const u16* __restrict__ A,
                                                  const u16* __restrict__ B,
                                                  const float* __restrict__ bias,
                                                  float* __restrict__ C,
                                                  float* __restrict__ Cp,
                                                  int M, int N, int K) {
    __shared__ __attribute__((aligned(16))) u16 Ash[128 * 64];
    __shared__ __attribute__((aligned(16))) u16 Bsh[128 * 64];
    int tid = threadIdx.x;
    int m0 = blockIdx.y * 128, n0 = blockIdx.x * 128;
    int klen = K / gridDim.z;
    int kbeg = blockIdx.z * klen, kend = kbeg + klen;
    int wave = tid >> 6, lane = tid & 63;
    int l16 = lane & 15, quad = lane >> 4;
    int wr = wave >> 1, wc = wave & 1;
    int lrow = lane >> 3, lcol = lane & 7;      // staging: 8 rows x 8 chunks(16B)
    int scol = lcol ^ lrow;                     // pre-swizzled source chunk
    int sw = l16 & 7;                           // read-side swizzle key (= row&7)

    f32x4 acc[4][4];
    f32x4 zero4 = {0.f, 0.f, 0.f, 0.f};
#pragma unroll
    for (int i = 0; i < 4; ++i)
#pragma unroll
        for (int j = 0; j < 4; ++j) acc[i][j] = zero4;

    for (int kk = kbeg; kk < kend; kk += 64) {
        __syncthreads();                         // WAR: prior ds_reads done
#pragma unroll
        for (int j = 0; j < 4; ++j) {
            int rbase = wave * 32 + j * 8;       // wave-uniform, 8-aligned
            size_t ga = (size_t)(m0 + rbase + lrow) * K + kk + scol * 8;
            size_t gb = (size_t)(n0 + rbase + lrow) * K + kk + scol * 8;
            GLL16(A + ga, &Ash[rbase * 64]);
            GLL16(B + gb, &Bsh[rbase * 64]);
        }
        __syncthreads();                         // vmcnt(0) drain -> data visible
#pragma unroll
        for (int kc = 0; kc < 2; ++kc) {
            f16x8 af[4], bv[4];
#pragma unroll
            for (int i = 0; i < 4; ++i)
                af[i] = *(const f16x8*)&Ash[(wr * 64 + i * 16 + l16) * 64
                                            + (((kc * 4 + quad) ^ sw) << 3)];
#pragma unroll
            for (int j = 0; j < 4; ++j)
                bv[j] = *(const f16x8*)&Bsh[(wc * 64 + j * 16 + l16) * 64
                                            + (((kc * 4 + quad) ^ sw) << 3)];
#pragma unroll
            for (int i = 0; i < 4; ++i)
#pragma unroll
                for (int j = 0; j < 4; ++j)
                    acc[i][j] = __builtin_amdgcn_mfma_f32_16x16x32_f16(af[i], bv[j], acc[i][j], 0, 0, 0);
        }
    }
    float* dst = (blockIdx.z == 0) ? C : Cp;
    bool addb = (bias != nullptr) && (blockIdx.z == 0);
#pragma unroll
    for (int i = 0; i < 4; ++i)
#pragma unroll
        for (int r = 0; r < 4; ++r) {
            int row = m0 + wr * 64 + i * 16 + quad * 4 + r;
#pragma unroll
            for (int j = 0; j < 4; ++j) {
                int col = n0 + wc * 64 + j * 16 + l16;
                float v = acc[i][j][r];
                if (addb) v += bias[col];
                dst[(size_t)row * N + col] = v;
            }
        }
}

// ---- fp16 MFMA GEMM 256x256, 8-phase fine interleave (T2+T3+T4+T5) ----
// R15: R12's coarse 2-phase counted-vmcnt is the schedule m196 proved HURTS
// (-7..27% vs fine interleave). True 8-phase: per K-tile (slot s), 4 phases,
// each {stage ONE half-tile of t+1 into slot s^1 (2 GLL16) | ds_read one
// C-quadrant's fragments | 16 MFMA (setprio) | s_barrier}. Phase 0 also does
// the per-tile wait: vmcnt(2) after issuing 2 new loads -> in-order retire
// means ALL of tile t landed, only 2 newest in flight (never drains mid-loop).
// Race-freedom: (a) reads of slot s gated by entry vmcnt("memory" fence) +
// s_barrier; (b) writes into s^1 issue only after prev iter's phase-3-end
// barrier, by which every wave's reads of s^1 completed (ds_read data is
// consumed at the compiler's lgkmcnt before that iter's last MFMAs).
// sched_barrier(0) pins every asm boundary (R12-verified discipline).
__global__ __launch_bounds__(512) void k_gemm256(const u16* __restrict__ A,
                                                 const u16* __restrict__ B,
                                                 const float* __restrict__ bias,
                                                 float* __restrict__ C,
                                                 float* __restrict__ Cp,
                                                 int M, int N, int K) {
    __shared__ __attribute__((aligned(16))) u16 Ash[2][256 * 64];
    __shared__ __attribute__((aligned(16))) u16 Bsh[2][256 * 64];
    int tid = threadIdx.x;
    int m0 = blockIdx.y * 256, n0 = blockIdx.x * 256;
    int klen = K / gridDim.z;
    int kbeg = blockIdx.z * klen;
    int NT = klen >> 6;
    int wave = tid >> 6, lane = tid & 63;
    int l16 = lane & 15, quad = lane >> 4;
    int wr = wave >> 2, wc = wave & 3;          // 2 x 4 wave grid
    int lrow = lane >> 3, lcol = lane & 7;      // staging: 8 rows x 8 chunks(16B)
    int scol = lcol ^ lrow;                     // pre-swizzled source chunk
    int sw = l16 & 7;                           // read-side swizzle key (= row&7)

    f32x4 acc[8][4];
    f32x4 zero4 = {0.f, 0.f, 0.f, 0.f};
#pragma unroll
    for (int i = 0; i < 8; ++i)
#pragma unroll
        for (int j = 0; j < 4; ++j) acc[i][j] = zero4;

    // stage one 128-row half of A or B for tile tt into slot ss (2 GLL16/thread)
#define STG_A(tt, hh, ss) do {                                            \
    size_t ko_ = (size_t)kbeg + (size_t)(tt) * 64;                        \
    _Pragma("unroll")                                                     \
    for (int j_ = 0; j_ < 2; ++j_) {                                      \
        int rb_ = (hh) * 128 + wave * 16 + j_ * 8;                        \
        GLL16(A + (size_t)(m0 + rb_ + lrow) * K + ko_ + scol * 8,         \
              &Ash[ss][rb_ * 64]);                                        \
    } } while (0)
#define STG_B(tt, hh, ss) do {                                            \
    size_t ko_ = (size_t)kbeg + (size_t)(tt) * 64;                        \
    _Pragma("unroll")                                                     \
    for (int j_ = 0; j_ < 2; ++j_) {                                      \
        int rb_ = (hh) * 128 + wave * 16 + j_ * 8;                        \
        GLL16(B + (size_t)(n0 + rb_ + lrow) * K + ko_ + scol * 8,         \
              &Bsh[ss][rb_ * 64]);                                        \
    } } while (0)

    // prologue: full tile 0 -> slot 0 (8 loads/thread)
    STG_A(0, 0, 0); STG_A(0, 1, 0); STG_B(0, 0, 0); STG_B(0, 1, 0);

    for (int t = 0; t < NT; ++t) {
        int s = t & 1, s2 = s ^ 1;
        bool pf = (t + 1 < NT);

        // ---- phase 0: stage A-half0(t+1) | wait tile t | bv + quadrant 0 ----
        if (pf) {
            STG_A(t + 1, 0, s2);
            __builtin_amdgcn_sched_barrier(0);
            asm volatile("s_waitcnt vmcnt(2)" ::: "memory");  // tile t landed
        } else {
            __builtin_amdgcn_sched_barrier(0);
            asm volatile("s_waitcnt vmcnt(0)" ::: "memory");  // tail drain
        }
        __builtin_amdgcn_sched_barrier(0);
        __builtin_amdgcn_s_barrier();            // all waves: tile t visible
        __builtin_amdgcn_sched_barrier(0);

        f16x8 bv[4][2];                          // B fragments persist all phases
#pragma unroll
        for (int j = 0; j < 4; ++j)
#pragma unroll
            for (int kc = 0; kc < 2; ++kc)
                bv[j][kc] = *(const f16x8*)&Bsh[s][(wc * 64 + j * 16 + l16) * 64
                                                   + (((kc * 4 + quad) ^ sw) << 3)];

#pragma unroll
        for (int q = 0; q < 4; ++q) {            // 4 phases = 4 C-quadrants
            if (q == 1 && pf) STG_A(t + 1, 1, s2);
            if (q == 2 && pf) STG_B(t + 1, 0, s2);
            if (q == 3 && pf) STG_B(t + 1, 1, s2);
            f16x8 af[2][2];
#pragma unroll
            for (int i = 0; i < 2; ++i)
#pragma unroll
                for (int kc = 0; kc < 2; ++kc)
                    af[i][kc] = *(const f16x8*)&Ash[s][(wr * 128 + (q * 2 + i) * 16 + l16) * 64
                                                       + (((kc * 4 + quad) ^ sw) << 3)];
            __builtin_amdgcn_s_setprio(1);
#pragma unroll
            for (int kc = 0; kc < 2; ++kc)
#pragma unroll
                for (int i = 0; i < 2; ++i)
#pragma unroll
                    for (int j = 0; j < 4; ++j)
                        acc[q * 2 + i][j] = __builtin_amdgcn_mfma_f32_16x16x32_f16(
                            af[i][kc], bv[j][kc], acc[q * 2 + i][j], 0, 0, 0);
            __builtin_amdgcn_s_setprio(0);
            __builtin_amdgcn_sched_barrier(0);
            __builtin_amdgcn_s_barrier();        // phase end (q=3: guards s2 reuse)
            __builtin_amdgcn_sched_barrier(0);
        }
    }
#undef STG_A
#undef STG_B

    float* dst = (blockIdx.z == 0) ? C : Cp;
    bool addb = (bias != nullptr) && (blockIdx.z == 0);
#pragma unroll
    for (int i = 0; i < 8; ++i)
#pragma unroll
        for (int r = 0; r < 4; ++r) {
            int row = m0 + wr * 128 + i * 16 + quad * 4 + r;
#pragma unroll
            for (int j = 0; j < 4; ++j) {
                int col = n0 + wc * 64 + j * 16 + l16;
                float v = acc[i][j][r];
                if (addb) v += bias[col];
                dst[(size_t)row * N + col] = v;
            }
        }
}

// ---- out += partial (fp32, float4) ----
__global__ void k_reduce(float* __restrict__ out, const float* __restrict__ part, int n4) {
    int i = blockIdx.x * 256 + threadIdx.x;
    if (i >= n4) return;
    float4 a = ((const float4*)out)[i];
    float4 b = ((const float4*)part)[i];
    a.x += b.x; a.y += b.y; a.z += b.z; a.w += b.w;
    ((float4*)out)[i] = a;
}

// ---- fused RoPE + V-transpose (disjoint column ranges of Y) ----
__global__ __launch_bounds__(256) void k_ropevt(const float* __restrict__ Y,
                                                const float* __restrict__ Yp,
                                                const int* __restrict__ pos,
                                                u16* __restrict__ Qh, u16* __restrict__ Ql,
                                                u16* __restrict__ Kh,
                                                u16* __restrict__ Vt) {
    int tid = threadIdx.x;
    if (blockIdx.x < 2048) {
        __shared__ double finv[64];
        if (tid < 64)   // inv_freq = theta^(-i/64) = 2^(-i*log2(1e6)/64)
            finv[tid] = exp2(-0.3114307588956902 * (double)tid);
        __syncthreads();
        int s = blockIdx.x;
        double p = (double)pos[s];
        const float* y  = Y + (size_t)s * NQKV;
        const float* yp = Yp ? (Yp + (size_t)s * NQKV) : nullptr;
        const float QSCALE = 0.1275174313f;     // (1/sqrt(128)) * log2(e)
        for (int u = tid; u < 2048; u += 256) {
            int blk = u >> 6, i = u & 63;
            int idx  = blk * 128 + i;
            int idx2 = idx + 64;
            double ang = p * finv[i];
            double n = rint(ang * 0.15915494309189535);          // /(2*pi)
            float r = (float)fma(-6.283185307179586, n, ang);    // range-reduced angle
            float sn, cs;
            __sincosf(r, &sn, &cs);
            float v1 = y[idx], v2 = y[idx2];
            if (yp) { v1 += yp[idx]; v2 += yp[idx2]; }
            float o1 = v1 * cs - v2 * sn;
            float o2 = v2 * cs + v1 * sn;
            if (idx < 3584) {
                u16 hh, ll;
                split2(o1 * QSCALE, hh, ll);
                Qh[(size_t)s * 3584 + idx] = hh;
                Ql[(size_t)s * 3584 + idx] = ll;
                split2(o2 * QSCALE, hh, ll);
                Qh[(size_t)s * 3584 + idx2] = hh;
                Ql[(size_t)s * 3584 + idx2] = ll;
            } else {
                Kh[(size_t)s * 512 + (idx  - 3584)] = f2h(o1);
                Kh[(size_t)s * 512 + (idx2 - 3584)] = f2h(o2);
            }
        }
    } else {
        __shared__ __attribute__((aligned(16))) u16 T[64][72];
        int local = blockIdx.x - 2048;
        int s0 = (local % 32) * 64, d0 = (local / 32) * 64;
#pragma unroll
        for (int t = 0; t < 16; ++t) {
            int idx = tid + t * 256;
            int r = idx >> 6, c = idx & 63;
            size_t goff = (size_t)(s0 + r) * NQKV + 4096 + d0 + c;
            float val = Y[goff];
            if (Yp) val += Yp[goff];
            T[c][r] = f2h(val);
        }
        __syncthreads();
#pragma unroll
        for (int t = 0; t < 2; ++t) {
            int cc = tid + t * 256;
            int dr = cc >> 3, s8 = (cc & 7) << 3;
            *(u16x8*)(Vt + (size_t)(d0 + dr) * Sq + s0 + s8) = *(const u16x8*)&T[dr][s8];
        }
    }
}

// ---- flash attention fp16: persistent blocks, LPT queue, reg-prefetch ----
// EXACT R7-verified body (121us, VGPR 124, 4 blocks/CU). Lessons pinned:
//  R3: no min-waves clamp. R5: no device fences in-loop. R8: staging is
//  software prefetch, keep it. R9: VGPR=124 is 4 below the 128 cliff --
//  do not add registers.
__global__ __launch_bounds__(256) void k_attn(const u16* __restrict__ Qh,
                                              const u16* __restrict__ Ql,
                                              const u16* __restrict__ Kh,
                                              const u16* __restrict__ Vt,
                                              u16* __restrict__ AO,
                                              int* __restrict__ ctr) {
    __shared__ __attribute__((aligned(16))) u16 Ks[64][128];   // 16384 B, swizzled
    __shared__ __attribute__((aligned(16))) u16 Vs[128][64];   // 16384 B, swizzled
    __shared__ __attribute__((aligned(16))) u16 Ps[4][16][64]; //  8192 B, swizzled

    int tid = threadIdx.x;
    int wave = tid >> 6, lane = tid & 63, l16 = lane & 15, quad = lane >> 4;
    int sw = l16 & 7;                       // read-side swizzle key (= row&7)

    for (;;) {
        __syncthreads();                   // all waves done with prior item
        if (tid == 0) *(int*)&Ks[0][0] = atomicAdd(ctr, 1);
        __syncthreads();
        int item = *(const int*)&Ks[0][0];
        if (item >= 32 * NH) break;        // block-uniform exit
        int qt = 31 - item / NH;           // longest first (LPT)
        int h  = item % NH;
        int q0 = qt * 64;
        int kvh = h / 7;                   // NH/NKV = 7
        __syncthreads();                   // item slot read by all before staging

        const u16* Kbase = Kh + kvh * HD;                  // row stride 512
        const u16* Vbase = Vt + (size_t)(kvh * HD) * Sq;   // row stride Sq

        // Q fragments hi/lo direct from global (A-layout: m=l16, k=quad*8+j)
        f16x8 qfh[4], qfl[4];
        {
            size_t qoff = (size_t)(q0 + wave * 16 + l16) * Hdim + h * HD + quad * 8;
#pragma unroll
            for (int kc = 0; kc < 4; ++kc) {
                qfh[kc] = *(const f16x8*)(Qh + qoff + kc * 32);
                qfl[kc] = *(const f16x8*)(Ql + qoff + kc * 32);
            }
        }

        // initial staging of tile 0 (swizzled writes)
#pragma unroll
        for (int t = 0; t < 4; ++t) {
            int c = tid + t * 256;
            int row = c >> 4, ch = (c & 15) ^ (row & 7);
            *(u16x8*)&Ks[row][ch << 3] = *(const u16x8*)(Kbase + (size_t)row * 512 + ((c & 15) << 3));
        }
#pragma unroll
        for (int t = 0; t < 4; ++t) {
            int c = tid + t * 256;
            int d = c >> 3, ch = (c & 7) ^ (d & 7);
            *(u16x8*)&Vs[d][ch << 3] = *(const u16x8*)(Vbase + (size_t)d * Sq + ((c & 7) << 3));
        }
        __syncthreads();

        f32x4 O[8];
        f32x4 zero4 = {0.f, 0.f, 0.f, 0.f};
#pragma unroll
        for (int t = 0; t < 8; ++t) O[t] = zero4;
        float mrow[4], lrow[4];
#pragma unroll
        for (int r = 0; r < 4; ++r) { mrow[r] = -1e30f; lrow[r] = 0.f; }

        for (int kt = 0; kt <= qt; ++kt) {
            int k0 = kt * 64;
            int kn = (kt < qt) ? k0 + 64 : k0;     // clamped prefetch base

            // ---- issue next-tile loads into registers (latency overlapped) ----
            u16x8 nk[4], nv[4];
#pragma unroll
            for (int t = 0; t < 4; ++t) {
                int c = tid + t * 256;
                nk[t] = *(const u16x8*)(Kbase + (size_t)(kn + (c >> 4)) * 512 + ((c & 15) << 3));
                nv[t] = *(const u16x8*)(Vbase + (size_t)(c >> 3) * Sq + kn + ((c & 7) << 3));
            }

            // ---- compute current tile from LDS (log2-domain scores) ----
            f32x4 sa[4];                       // S = Q K^T, 2-term split
            __builtin_amdgcn_s_setprio(1);
#pragma unroll
            for (int ct = 0; ct < 4; ++ct) {
                f32x4 z = zero4;
#pragma unroll
                for (int kc = 0; kc < 4; ++kc) {
                    f16x8 b = *(const f16x8*)&Ks[ct * 16 + l16][(((kc * 4 + quad) ^ sw)) << 3];
                    z = __builtin_amdgcn_mfma_f32_16x16x32_f16(qfh[kc], b, z, 0, 0, 0);
                    z = __builtin_amdgcn_mfma_f32_16x16x32_f16(qfl[kc], b, z, 0, 0, 0);
                }
                sa[ct] = z;
            }
            __builtin_amdgcn_s_setprio(0);
            if (kt == qt) {
#pragma unroll
                for (int ct = 0; ct < 4; ++ct)
#pragma unroll
                    for (int r = 0; r < 4; ++r)
                        if (k0 + ct * 16 + l16 > q0 + wave * 16 + quad * 4 + r) sa[ct][r] = -1e30f;
            }
            // row max of this tile
            float pmax[4];
#pragma unroll
            for (int r = 0; r < 4; ++r) {
                float mx = fmaxf(fmaxf(sa[0][r], sa[1][r]), fmaxf(sa[2][r], sa[3][r]));
#pragma unroll
                for (int off = 1; off < 16; off <<= 1)
                    mx = fmaxf(mx, __shfl_xor(mx, off, 64));
                pmax[r] = mx;
            }
            // T13 defer-max: skip rescale while max growth <= 8 (P <= 2^8)
            bool keep = (pmax[0] <= mrow[0] + 8.f) && (pmax[1] <= mrow[1] + 8.f) &&
                        (pmax[2] <= mrow[2] + 8.f) && (pmax[3] <= mrow[3] + 8.f);
            if (!__all(keep)) {
#pragma unroll
                for (int r = 0; r < 4; ++r) {
                    float mnew = fmaxf(mrow[r], pmax[r]);
                    float alpha = exp2f(mrow[r] - mnew);
                    mrow[r] = mnew;
                    lrow[r] *= alpha;
#pragma unroll
                    for (int ct = 0; ct < 8; ++ct) O[ct][r] *= alpha;
                }
            }
            float rs[4] = {0.f, 0.f, 0.f, 0.f};
#pragma unroll
            for (int ct = 0; ct < 4; ++ct)
#pragma unroll
                for (int r = 0; r < 4; ++r) {
                    float p = exp2f(sa[ct][r] - mrow[r]);
                    rs[r] += p;
                    // swizzled Ps write: chunk ^= row&7, row = quad*4+r
                    Ps[wave][quad * 4 + r][(ct * 16 + l16) ^ (((quad * 4 + r) & 7) << 3)] = f2h(p);
                }
#pragma unroll
            for (int r = 0; r < 4; ++r) {
#pragma unroll
                for (int off = 1; off < 16; off <<= 1)
                    rs[r] += __shfl_xor(rs[r], off, 64);
                lrow[r] += rs[r];
            }
            __builtin_amdgcn_s_setprio(1);
#pragma unroll
            for (int kc = 0; kc < 2; ++kc) {   // PV from LDS (Ps wave-private)
                f16x8 a = *(const f16x8*)&Ps[wave][l16][(((kc * 4 + quad) ^ sw)) << 3];
#pragma unroll
                for (int ct = 0; ct < 8; ++ct) {
                    f16x8 b = *(const f16x8*)&Vs[ct * 16 + l16][(((kc * 4 + quad) ^ sw)) << 3];
                    O[ct] = __builtin_amdgcn_mfma_f32_16x16x32_f16(a, b, O[ct], 0, 0, 0);
                }
            }
            __builtin_amdgcn_s_setprio(0);

            // ---- commit prefetched tile to LDS (swizzled) ----
            __syncthreads();                   // all waves done reading Ks/Vs
#pragma unroll
            for (int t = 0; t < 4; ++t) {
                int c = tid + t * 256;
                int row = c >> 4, chk = ((c & 15) ^ (row & 7));
                int d = c >> 3, chv = ((c & 7) ^ (d & 7));
                *(u16x8*)&Ks[row][chk << 3] = nk[t];
                *(u16x8*)&Vs[d][chv << 3]   = nv[t];
            }
            __syncthreads();                   // staged data visible
        }
#pragma unroll
        for (int r = 0; r < 4; ++r) {
            float inv = 1.f / lrow[r];
            int row = q0 + wave * 16 + quad * 4 + r;
#pragma unroll
            for (int ct = 0; ct < 8; ++ct)
                AO[(size_t)row * 3584 + h * HD + ct * 16 + l16] = f2h(O[ct][r] * inv);
        }
    }
}

extern "C" void kernel_launch(void* const* d_in, const int* in_sizes, int n_in,
                              void* d_out, int out_size, void* d_ws, size_t ws_size,
                              hipStream_t stream) {
    (void)in_sizes; (void)n_in; (void)out_size;
    const float* hidden = (const float*)d_in[0];
    const int*   pos    = (const int*)d_in[1];
    const int*   qw_q = (const int*)d_in[2];
    const int*   qz_q = (const int*)d_in[3];
    const float* sc_q = (const float*)d_in[4];
    const float* b_q  = (const float*)d_in[5];
    const int*   qw_k = (const int*)d_in[6];
    const int*   qz_k = (const int*)d_in[7];
    const float* sc_k = (const float*)d_in[8];
    const float* b_k  = (const float*)d_in[9];
    const int*   qw_v = (const int*)d_in[10];
    const int*   qz_v = (const int*)d_in[11];
    const float* sc_v = (const float*)d_in[12];
    const float* b_v  = (const float*)d_in[13];
    const int*   qw_o = (const int*)d_in[14];
    const int*   qz_o = (const int*)d_in[15];
    const float* sc_o = (const float*)d_in[16];
    float* out = (float*)d_out;

    char* base = (char*)d_ws;
    size_t off = 0;
    auto alloc = [&](size_t bytes) {
        char* p = base + off;
        off += (bytes + 255) & ~(size_t)255;
        return p;
    };
    u16* Wh = (u16*)alloc((size_t)NQKV * KD * 2);   // 33.0 MB (reused for W_o fallback)
    u16* Xh = (u16*)alloc((size_t)Sq * Hdim * 2);   // 14.7 MB (reused as Qh, then partial)
    u16* Xl = (u16*)alloc((size_t)Sq * Hdim * 2);   // 14.7 MB (Ql, then partial)
    float* Y = (float*)alloc((size_t)Sq * NQKV * 4);// 37.7 MB (reused for AO)
    u16* Khb = (u16*)alloc((size_t)Sq * 512 * 2);   //  2.1 MB
    u16* Vt  = (u16*)alloc((size_t)512 * Sq * 2);   //  2.1 MB
    float* biasc = (float*)alloc(NQKV * 4);
    int*   ctr   = (int*)alloc(4096);               // attn work-queue counter
    // split-K partial for GEMM1 (live GEMM1 -> ropevt); gated on ws_size
    float* Part1 = (float*)alloc((size_t)Sq * NQKV * 4);   // 37.7 MB
    bool deep = (off <= ws_size);
    u16* Wo2 = (u16*)alloc((size_t)3584 * KD * 2);  // 25.7 MB (deq_o target in k_pre)
    bool deep2 = (off <= ws_size);
    u16* Qhb = Xh;                 // Xh dead after GEMM1
    u16* Qlb = Xl;
    u16* AO  = (u16*)Y;            // Y dead after rope/vtrans
    u16* Wo  = Wh;                 // Wh dead after GEMM1 (fallback W_o dst)
    float* Part = (float*)Xh;      // Xh+Xl contiguous = 29.4 MB, dead after attn

    hipMemsetAsync(ctr, 0, 4096, stream);           // ws is re-poisoned each call
    // fused preprocessing: cvt(3584) | bias(18) | deq_q(3136) | deq_k(448)
    //                    | deq_v(448) | deq_o(3136, only if deep2)
    int preBlocks = 3584 + 18 + 3136 + 448 + 448 + (deep2 ? 3136 : 0);
    k_pre<<<preBlocks, 256, 0, stream>>>(hidden, Xh, b_q, b_k, b_v, biasc,
                                         qw_q, qz_q, sc_q, qw_k, qz_k, sc_k,
                                         qw_v, qz_v, sc_v, qw_o, qz_o, sc_o,
                                         Wh, deep2 ? Wo2 : nullptr);
    // GEMM1: 128^2, split-K=2 (1152 blocks = 4.5/CU, best measured: 123us);
    // partial folded into ropevt.
    if (deep) {
        k_gemm_f16<<<dim3(NQKV / 128, Sq / 128, 2), 256, 0, stream>>>(Xh, Wh, biasc, Y, Part1, Sq, NQKV, KD);
    } else {
        k_gemm_f16<<<dim3(NQKV / 128, Sq / 128, 1), 256, 0, stream>>>(Xh, Wh, biasc, Y, nullptr, Sq, NQKV, KD);
    }
    k_ropevt<<<2304, 256, 0, stream>>>(Y, deep ? Part1 : nullptr, pos, Qhb, Qlb, Khb, Vt);
    if (!deep2)   // fallback: dequant W_o into Wh after GEMM1 consumed it
        k_dequant<<<dim3(56, 56), 256, 0, stream>>>(qw_o, qz_o, sc_o, Wo, 3584);
    k_attn<<<dim3(1024), 256, 0, stream>>>(Qhb, Qlb, Khb, Vt, AO, ctr);
    // GEMM2: 256^2 8-phase z=2 (224 blocks) + reduce.
    k_gemm256<<<dim3(Hdim / 256, Sq / 256, 2), 512, 0, stream>>>(AO, deep2 ? Wo2 : Wo, nullptr, out, Part, Sq, Hdim, KD);
    k_reduce<<<(Sq * Hdim / 4 + 255) / 256, 256, 0, stream>>>(out, Part, Sq * Hdim / 4);
}

// Round 16
// 438.455 us; speedup vs baseline: 1.0585x; 1.0585x over previous
//
#include <hip/hip_runtime.h>

// ---- problem constants ----
#define Hdim   3584
#define NH     28
#define NKV    4
#define HD     128
#define Sq     2048
#define NQKV   4608          // 3584 q + 512 k + 512 v
#define KD     3584          // inner dim of both GEMMs

typedef unsigned short u16;
typedef unsigned int   u32;
typedef _Float16 f16;
typedef _Float16 f16x8 __attribute__((ext_vector_type(8)));     // MFMA A/B operand (4 VGPRs)
typedef unsigned short u16x8 __attribute__((ext_vector_type(8)));
typedef float f32x4 __attribute__((ext_vector_type(4)));        // MFMA C/D operand

__device__ __forceinline__ u16 f2h(float x) { f16 h = (f16)x; return __builtin_bit_cast(u16, h); }
__device__ __forceinline__ float h2f(u16 b) { return (float)__builtin_bit_cast(f16, b); }
__device__ __forceinline__ void split2(float x, u16& hi, u16& lo) {
    hi = f2h(x);
    lo = f2h(x - h2f(hi));   // combined ~22-bit mantissa
}

// async global->LDS, 16B per lane; LDS dest = wave-uniform base + lane*16
#define GLL16(gp, lp) __builtin_amdgcn_global_load_lds( \
    (__attribute__((address_space(1))) void*)(gp),      \
    (__attribute__((address_space(3))) void*)(lp), 16, 0, 0)

// ---- AWQ dequant tile body (R7-verified): 64x64 tile via coalesced LDS ----
__device__ __forceinline__ void deq_tile(const int* __restrict__ qw,
                                         const int* __restrict__ qz,
                                         const float* __restrict__ sc,
                                         u16* __restrict__ W, int dout,
                                         int bx, int by, int tid,
                                         u32 (*L)[9], float* scl, u32* zq) {
    int w8 = dout >> 3;
    int c0 = bx * 64, j0 = bx * 8;
    int r0 = by * 64, g = r0 >> 7;               // G=128 -> uniform per tile
#pragma unroll
    for (int t = 0; t < 2; ++t) {
        int u = tid + t * 256;
        int rr = u >> 3, jj = u & 7;             // coalesced: 8 consecutive words/row
        L[rr][jj] = (u32)qw[(size_t)(r0 + rr) * w8 + j0 + jj];
    }
    if (tid < 64) scl[tid] = sc[(size_t)g * dout + c0 + tid];
    if (tid < 8)  zq[tid]  = (u32)qz[(size_t)g * w8 + j0 + tid];
    __syncthreads();
#pragma unroll
    for (int t = 0; t < 2; ++t) {
        int u = tid + t * 256;
        int lc = u >> 3, r8 = (u & 7) << 3;      // chunk: col c0+lc, rows r0+r8..+7
        int sh = (lc & 7) << 2, jc = lc >> 3;
        int z = (int)((zq[jc] >> sh) & 15u);
        float s = scl[lc];
        u16x8 v;
#pragma unroll
        for (int i = 0; i < 8; ++i) {
            int w = (int)((L[r8 + i][jc] >> sh) & 15u);
            v[i] = f2h((float)(w - z) * s);
        }
        *(u16x8*)(W + (size_t)(c0 + lc) * KD + r0 + r8) = v;
    }
}

// ---- fused preprocessing: cvt | bias | deq_q | deq_k | deq_v | [deq_o] ----
// R11-verified. deq_o writes Wo2 (separate buffer, safe before GEMM1).
__global__ __launch_bounds__(256) void k_pre(const float* __restrict__ hidden,
                                             u16* __restrict__ Xh,
                                             const float* __restrict__ bq,
                                             const float* __restrict__ bk,
                                             const float* __restrict__ bv,
                                             float* __restrict__ biasc,
                                             const int* qwq, const int* qzq, const float* scq,
                                             const int* qwk, const int* qzk, const float* sck,
                                             const int* qwv, const int* qzv, const float* scv,
                                             const int* qwo, const int* qzo, const float* sco,
                                             u16* __restrict__ Wh,
                                             u16* __restrict__ Wo2) {
    __shared__ u32 L[64][9];
    __shared__ float scl[64];
    __shared__ u32 zq[8];
    int b = blockIdx.x, tid = threadIdx.x;
    if (b < 3584) {                              // fp32 -> fp16, 8 elems/thread
        int i = b * 256 + tid;
        const float4* p = (const float4*)(hidden + (size_t)i * 8);
        float4 a = p[0], c = p[1];
        float v[8] = {a.x, a.y, a.z, a.w, c.x, c.y, c.z, c.w};
        u16x8 h;
#pragma unroll
        for (int j = 0; j < 8; ++j) h[j] = f2h(v[j]);
        *(u16x8*)(Xh + (size_t)i * 8) = h;
        return;
    }
    b -= 3584;
    if (b < 18) {                                // concat biases (q|k|v)
        int i = b * 256 + tid;
        if (i < NQKV)
            biasc[i] = (i < 3584) ? bq[i] : (i < 4096 ? bk[i - 3584] : bv[i - 4096]);
        return;
    }
    b -= 18;
    if (b < 3136) { deq_tile(qwq, qzq, scq, Wh, 3584, b % 56, b / 56, tid, L, scl, zq); return; }
    b -= 3136;
    if (b < 448)  { deq_tile(qwk, qzk, sck, Wh + (size_t)3584 * KD, 512, b % 8, b / 8, tid, L, scl, zq); return; }
    b -= 448;
    if (b < 448)  { deq_tile(qwv, qzv, scv, Wh + (size_t)4096 * KD, 512, b % 8, b / 8, tid, L, scl, zq); return; }
    b -= 448;
    deq_tile(qwo, qzo, sco, Wo2, 3584, b % 56, b / 56, tid, L, scl, zq);
}

// ---- standalone dequant (fallback when Wo2 doesn't fit the workspace) ----
__global__ __launch_bounds__(256) void k_dequant(const int* __restrict__ qw,
                                                 const int* __restrict__ qz,
                                                 const float* __restrict__ sc,
                                                 u16* __restrict__ W, int dout) {
    __shared__ u32 L[64][9];
    __shared__ float scl[64];
    __shared__ u32 zq[8];
    deq_tile(qw, qz, sc, W, dout, blockIdx.x, blockIdx.y, threadIdx.x, L, scl, zq);
}

// ---- fp16 MFMA GEMM 128x128 (m97-style + T2 XOR-swizzle) ----
// GEMM1's config: 1152 blocks z=2 = 4.5/CU -> 550 TF, best of FOUR structures
// tried for this shape (256^2 coarse: 508; BK32 deep: 438; 8-phase fine:
// ~400 — R15). Block-level MLP beats 1-block/CU pipeline depth here.
// T2: chunk16B ^= row&7 on BOTH sides; measured conflicts = 0 (R4).
// R6: keep LINEAR block order (XCD chunking thrashed L3, FETCH +48%).
__global__ __launch_bounds__(256) void k_gemm_f16(const u16* __restrict__ A,
                                                  const u16* __restrict__ B,
                                                  const float* __restrict__ bias,
                                                  float* __restrict__ C,
                                                  float* __restrict__ Cp,
                                                  int M, int N, int K) {
    __shared__ __attribute__((aligned(16))) u16 Ash[128 * 64];
    __shared__ __attribute__((aligned(16))) u16 Bsh[128 * 64];
    int tid = threadIdx.x;
    int m0 = blockIdx.y * 128, n0 = blockIdx.x * 128;
    int klen = K / gridDim.z;
    int kbeg = blockIdx.z * klen, kend = kbeg + klen;
    int wave = tid >> 6, lane = tid & 63;
    int l16 = lane & 15, quad = lane >> 4;
    int wr = wave >> 1, wc = wave & 1;
    int lrow = lane >> 3, lcol = lane & 7;      // staging: 8 rows x 8 chunks(16B)
    int scol = lcol ^ lrow;                     // pre-swizzled source chunk
    int sw = l16 & 7;                           // read-side swizzle key (= row&7)

    f32x4 acc[4][4];
    f32x4 zero4 = {0.f, 0.f, 0.f, 0.f};
#pragma unroll
    for (int i = 0; i < 4; ++i)
#pragma unroll
        for (int j = 0; j < 4; ++j) acc[i][j] = zero4;

    for (int kk = kbeg; kk < kend; kk += 64) {
        __syncthreads();                         // WAR: prior ds_reads done
#pragma unroll
        for (int j = 0; j < 4; ++j) {
            int rbase = wave * 32 + j * 8;       // wave-uniform, 8-aligned
            size_t ga = (size_t)(m0 + rbase + lrow) * K + kk + scol * 8;
            size_t gb = (size_t)(n0 + rbase + lrow) * K + kk + scol * 8;
            GLL16(A + ga, &Ash[rbase * 64]);
            GLL16(B + gb, &Bsh[rbase * 64]);
        }
        __syncthreads();                         // vmcnt(0) drain -> data visible
#pragma unroll
        for (int kc = 0; kc < 2; ++kc) {
            f16x8 af[4], bv[4];
#pragma unroll
            for (int i = 0; i < 4; ++i)
                af[i] = *(const f16x8*)&Ash[(wr * 64 + i * 16 + l16) * 64
                                            + (((kc * 4 + quad) ^ sw) << 3)];
#pragma unroll
            for (int j = 0; j < 4; ++j)
                bv[j] = *(const f16x8*)&Bsh[(wc * 64 + j * 16 + l16) * 64
                                            + (((kc * 4 + quad) ^ sw) << 3)];
#pragma unroll
            for (int i = 0; i < 4; ++i)
#pragma unroll
                for (int j = 0; j < 4; ++j)
                    acc[i][j] = __builtin_amdgcn_mfma_f32_16x16x32_f16(af[i], bv[j], acc[i][j], 0, 0, 0);
        }
    }
    float* dst = (blockIdx.z == 0) ? C : Cp;
    bool addb = (bias != nullptr) && (blockIdx.z == 0);
#pragma unroll
    for (int i = 0; i < 4; ++i)
#pragma unroll
        for (int r = 0; r < 4; ++r) {
            int row = m0 + wr * 64 + i * 16 + quad * 4 + r;
#pragma unroll
            for (int j = 0; j < 4; ++j) {
                int col = n0 + wc * 64 + j * 16 + l16;
                float v = acc[i][j][r];
                if (addb) v += bias[col];
                dst[(size_t)row * N + col] = v;
            }
        }
}

// ---- fp16 MFMA GEMM 256x256, BK=64 2-slot counted-vmcnt (R12-verified) ----
// GEMM2 only: 128^2 grid gives 1.75 blocks/CU (431 TF); 256^2 z=2 (224
// blocks) trades MLP for 2x arithmetic intensity -> ~474 TF (~111us).
// R15 lesson: the finer 4-phase interleave REGRESSED here (~135us) — at
// 0.875 blocks/CU the extra per-phase barriers serialize with no co-resident
// block to hide them. This coarse schedule is the measured optimum.
__global__ __launch_bounds__(512) void k_gemm256(const u16* __restrict__ A,
                                                 const u16* __restrict__ B,
                                                 const float* __restrict__ bias,
                                                 float* __restrict__ C,
                                                 float* __restrict__ Cp,
                                                 int M, int N, int K) {
    __shared__ __attribute__((aligned(16))) u16 Ash[2][256 * 64];
    __shared__ __attribute__((aligned(16))) u16 Bsh[2][256 * 64];
    int tid = threadIdx.x;
    int m0 = blockIdx.y * 256, n0 = blockIdx.x * 256;
    int klen = K / gridDim.z;
    int kbeg = blockIdx.z * klen;
    int NT = klen >> 6;
    int wave = tid >> 6, lane = tid & 63;
    int l16 = lane & 15, quad = lane >> 4;
    int wr = wave >> 2, wc = wave & 3;          // 2 x 4 wave grid
    int lrow = lane >> 3, lcol = lane & 7;      // staging: 8 rows x 8 chunks(16B)
    int scol = lcol ^ lrow;                     // pre-swizzled source chunk
    int sw = l16 & 7;                           // read-side swizzle key (= row&7)

    f32x4 acc[8][4];
    f32x4 zero4 = {0.f, 0.f, 0.f, 0.f};
#pragma unroll
    for (int i = 0; i < 8; ++i)
#pragma unroll
        for (int j = 0; j < 4; ++j) acc[i][j] = zero4;

    // prologue: stage tile 0 into slot 0 (8 loads/lane)
#pragma unroll
    for (int j = 0; j < 4; ++j) {
        int rbase = (wave * 4 + j) * 8;          // wave-uniform, 8-aligned
        GLL16(A + (size_t)(m0 + rbase + lrow) * K + kbeg + scol * 8, &Ash[0][rbase * 64]);
        GLL16(B + (size_t)(n0 + rbase + lrow) * K + kbeg + scol * 8, &Bsh[0][rbase * 64]);
    }

    for (int t = 0; t < NT; ++t) {
        int s = t & 1;
        if (t + 1 < NT) {                        // issue next tile into other slot
            size_t ka = (size_t)kbeg + (size_t)(t + 1) * 64;
            int s2 = s ^ 1;
#pragma unroll
            for (int j = 0; j < 4; ++j) {
                int rbase = (wave * 4 + j) * 8;
                GLL16(A + (size_t)(m0 + rbase + lrow) * K + ka + scol * 8, &Ash[s2][rbase * 64]);
                GLL16(B + (size_t)(n0 + rbase + lrow) * K + ka + scol * 8, &Bsh[s2][rbase * 64]);
            }
            __builtin_amdgcn_sched_barrier(0);
            asm volatile("s_waitcnt vmcnt(8)" ::: "memory");   // tile t landed; 8 in flight
        } else {
            __builtin_amdgcn_sched_barrier(0);
            asm volatile("s_waitcnt vmcnt(0)" ::: "memory");   // last tile: drain once
        }
        __builtin_amdgcn_sched_barrier(0);
        __builtin_amdgcn_s_barrier();            // all waves: tile t visible
        __builtin_amdgcn_sched_barrier(0);

#pragma unroll
        for (int kc = 0; kc < 2; ++kc) {
            f16x8 af[8], bv[4];
#pragma unroll
            for (int i = 0; i < 8; ++i)
                af[i] = *(const f16x8*)&Ash[s][(wr * 128 + i * 16 + l16) * 64
                                              + (((kc * 4 + quad) ^ sw) << 3)];
#pragma unroll
            for (int j = 0; j < 4; ++j)
                bv[j] = *(const f16x8*)&Bsh[s][(wc * 64 + j * 16 + l16) * 64
                                              + (((kc * 4 + quad) ^ sw) << 3)];
            __builtin_amdgcn_s_setprio(1);
#pragma unroll
            for (int i = 0; i < 8; ++i)
#pragma unroll
                for (int j = 0; j < 4; ++j)
                    acc[i][j] = __builtin_amdgcn_mfma_f32_16x16x32_f16(af[i], bv[j], acc[i][j], 0, 0, 0);
            __builtin_amdgcn_s_setprio(0);
        }
        __builtin_amdgcn_sched_barrier(0);
        __builtin_amdgcn_s_barrier();            // reads done: slot s safe to overwrite
        __builtin_amdgcn_sched_barrier(0);
    }

    float* dst = (blockIdx.z == 0) ? C : Cp;
    bool addb = (bias != nullptr) && (blockIdx.z == 0);
#pragma unroll
    for (int i = 0; i < 8; ++i)
#pragma unroll
        for (int r = 0; r < 4; ++r) {
            int row = m0 + wr * 128 + i * 16 + quad * 4 + r;
#pragma unroll
            for (int j = 0; j < 4; ++j) {
                int col = n0 + wc * 64 + j * 16 + l16;
                float v = acc[i][j][r];
                if (addb) v += bias[col];
                dst[(size_t)row * N + col] = v;
            }
        }
}

// ---- out += partial (fp32, float4) ----
__global__ void k_reduce(float* __restrict__ out, const float* __restrict__ part, int n4) {
    int i = blockIdx.x * 256 + threadIdx.x;
    if (i >= n4) return;
    float4 a = ((const float4*)out)[i];
    float4 b = ((const float4*)part)[i];
    a.x += b.x; a.y += b.y; a.z += b.z; a.w += b.w;
    ((float4*)out)[i] = a;
}

// ---- fused RoPE + V-transpose (disjoint column ranges of Y) ----
__global__ __launch_bounds__(256) void k_ropevt(const float* __restrict__ Y,
                                                const float* __restrict__ Yp,
                                                const int* __restrict__ pos,
                                                u16* __restrict__ Qh, u16* __restrict__ Ql,
                                                u16* __restrict__ Kh,
                                                u16* __restrict__ Vt) {
    int tid = threadIdx.x;
    if (blockIdx.x < 2048) {
        __shared__ double finv[64];
        if (tid < 64)   // inv_freq = theta^(-i/64) = 2^(-i*log2(1e6)/64)
            finv[tid] = exp2(-0.3114307588956902 * (double)tid);
        __syncthreads();
        int s = blockIdx.x;
        double p = (double)pos[s];
        const float* y  = Y + (size_t)s * NQKV;
        const float* yp = Yp ? (Yp + (size_t)s * NQKV) : nullptr;
        const float QSCALE = 0.1275174313f;     // (1/sqrt(128)) * log2(e)
        for (int u = tid; u < 2048; u += 256) {
            int blk = u >> 6, i = u & 63;
            int idx  = blk * 128 + i;
            int idx2 = idx + 64;
            double ang = p * finv[i];
            double n = rint(ang * 0.15915494309189535);          // /(2*pi)
            float r = (float)fma(-6.283185307179586, n, ang);    // range-reduced angle
            float sn, cs;
            __sincosf(r, &sn, &cs);
            float v1 = y[idx], v2 = y[idx2];
            if (yp) { v1 += yp[idx]; v2 += yp[idx2]; }
            float o1 = v1 * cs - v2 * sn;
            float o2 = v2 * cs + v1 * sn;
            if (idx < 3584) {
                u16 hh, ll;
                split2(o1 * QSCALE, hh, ll);
                Qh[(size_t)s * 3584 + idx] = hh;
                Ql[(size_t)s * 3584 + idx] = ll;
                split2(o2 * QSCALE, hh, ll);
                Qh[(size_t)s * 3584 + idx2] = hh;
                Ql[(size_t)s * 3584 + idx2] = ll;
            } else {
                Kh[(size_t)s * 512 + (idx  - 3584)] = f2h(o1);
                Kh[(size_t)s * 512 + (idx2 - 3584)] = f2h(o2);
            }
        }
    } else {
        __shared__ __attribute__((aligned(16))) u16 T[64][72];
        int local = blockIdx.x - 2048;
        int s0 = (local % 32) * 64, d0 = (local / 32) * 64;
#pragma unroll
        for (int t = 0; t < 16; ++t) {
            int idx = tid + t * 256;
            int r = idx >> 6, c = idx & 63;
            size_t goff = (size_t)(s0 + r) * NQKV + 4096 + d0 + c;
            float val = Y[goff];
            if (Yp) val += Yp[goff];
            T[c][r] = f2h(val);
        }
        __syncthreads();
#pragma unroll
        for (int t = 0; t < 2; ++t) {
            int cc = tid + t * 256;
            int dr = cc >> 3, s8 = (cc & 7) << 3;
            *(u16x8*)(Vt + (size_t)(d0 + dr) * Sq + s0 + s8) = *(const u16x8*)&T[dr][s8];
        }
    }
}

// ---- flash attention fp16: persistent blocks, LPT queue, reg-prefetch ----
// EXACT R7-verified body (121us, VGPR 124, 4 blocks/CU). Lessons pinned:
//  R3: no min-waves clamp. R5: no device fences in-loop. R8: staging is
//  software prefetch, keep it. R9: VGPR=124 is 4 below the 128 cliff --
//  do not add registers.
__global__ __launch_bounds__(256) void k_attn(const u16* __restrict__ Qh,
                                              const u16* __restrict__ Ql,
                                              const u16* __restrict__ Kh,
                                              const u16* __restrict__ Vt,
                                              u16* __restrict__ AO,
                                              int* __restrict__ ctr) {
    __shared__ __attribute__((aligned(16))) u16 Ks[64][128];   // 16384 B, swizzled
    __shared__ __attribute__((aligned(16))) u16 Vs[128][64];   // 16384 B, swizzled
    __shared__ __attribute__((aligned(16))) u16 Ps[4][16][64]; //  8192 B, swizzled

    int tid = threadIdx.x;
    int wave = tid >> 6, lane = tid & 63, l16 = lane & 15, quad = lane >> 4;
    int sw = l16 & 7;                       // read-side swizzle key (= row&7)

    for (;;) {
        __syncthreads();                   // all waves done with prior item
        if (tid == 0) *(int*)&Ks[0][0] = atomicAdd(ctr, 1);
        __syncthreads();
        int item = *(const int*)&Ks[0][0];
        if (item >= 32 * NH) break;        // block-uniform exit
        int qt = 31 - item / NH;           // longest first (LPT)
        int h  = item % NH;
        int q0 = qt * 64;
        int kvh = h / 7;                   // NH/NKV = 7
        __syncthreads();                   // item slot read by all before staging

        const u16* Kbase = Kh + kvh * HD;                  // row stride 512
        const u16* Vbase = Vt + (size_t)(kvh * HD) * Sq;   // row stride Sq

        // Q fragments hi/lo direct from global (A-layout: m=l16, k=quad*8+j)
        f16x8 qfh[4], qfl[4];
        {
            size_t qoff = (size_t)(q0 + wave * 16 + l16) * Hdim + h * HD + quad * 8;
#pragma unroll
            for (int kc = 0; kc < 4; ++kc) {
                qfh[kc] = *(const f16x8*)(Qh + qoff + kc * 32);
                qfl[kc] = *(const f16x8*)(Ql + qoff + kc * 32);
            }
        }

        // initial staging of tile 0 (swizzled writes)
#pragma unroll
        for (int t = 0; t < 4; ++t) {
            int c = tid + t * 256;
            int row = c >> 4, ch = (c & 15) ^ (row & 7);
            *(u16x8*)&Ks[row][ch << 3] = *(const u16x8*)(Kbase + (size_t)row * 512 + ((c & 15) << 3));
        }
#pragma unroll
        for (int t = 0; t < 4; ++t) {
            int c = tid + t * 256;
            int d = c >> 3, ch = (c & 7) ^ (d & 7);
            *(u16x8*)&Vs[d][ch << 3] = *(const u16x8*)(Vbase + (size_t)d * Sq + ((c & 7) << 3));
        }
        __syncthreads();

        f32x4 O[8];
        f32x4 zero4 = {0.f, 0.f, 0.f, 0.f};
#pragma unroll
        for (int t = 0; t < 8; ++t) O[t] = zero4;
        float mrow[4], lrow[4];
#pragma unroll
        for (int r = 0; r < 4; ++r) { mrow[r] = -1e30f; lrow[r] = 0.f; }

        for (int kt = 0; kt <= qt; ++kt) {
            int k0 = kt * 64;
            int kn = (kt < qt) ? k0 + 64 : k0;     // clamped prefetch base

            // ---- issue next-tile loads into registers (latency overlapped) ----
            u16x8 nk[4], nv[4];
#pragma unroll
            for (int t = 0; t < 4; ++t) {
                int c = tid + t * 256;
                nk[t] = *(const u16x8*)(Kbase + (size_t)(kn + (c >> 4)) * 512 + ((c & 15) << 3));
                nv[t] = *(const u16x8*)(Vbase + (size_t)(c >> 3) * Sq + kn + ((c & 7) << 3));
            }

            // ---- compute current tile from LDS (log2-domain scores) ----
            f32x4 sa[4];                       // S = Q K^T, 2-term split
            __builtin_amdgcn_s_setprio(1);
#pragma unroll
            for (int ct = 0; ct < 4; ++ct) {
                f32x4 z = zero4;
#pragma unroll
                for (int kc = 0; kc < 4; ++kc) {
                    f16x8 b = *(const f16x8*)&Ks[ct * 16 + l16][(((kc * 4 + quad) ^ sw)) << 3];
                    z = __builtin_amdgcn_mfma_f32_16x16x32_f16(qfh[kc], b, z, 0, 0, 0);
                    z = __builtin_amdgcn_mfma_f32_16x16x32_f16(qfl[kc], b, z, 0, 0, 0);
                }
                sa[ct] = z;
            }
            __builtin_amdgcn_s_setprio(0);
            if (kt == qt) {
#pragma unroll
                for (int ct = 0; ct < 4; ++ct)
#pragma unroll
                    for (int r = 0; r < 4; ++r)
                        if (k0 + ct * 16 + l16 > q0 + wave * 16 + quad * 4 + r) sa[ct][r] = -1e30f;
            }
            // row max of this tile
            float pmax[4];
#pragma unroll
            for (int r = 0; r < 4; ++r) {
                float mx = fmaxf(fmaxf(sa[0][r], sa[1][r]), fmaxf(sa[2][r], sa[3][r]));
#pragma unroll
                for (int off = 1; off < 16; off <<= 1)
                    mx = fmaxf(mx, __shfl_xor(mx, off, 64));
                pmax[r] = mx;
            }
            // T13 defer-max: skip rescale while max growth <= 8 (P <= 2^8)
            bool keep = (pmax[0] <= mrow[0] + 8.f) && (pmax[1] <= mrow[1] + 8.f) &&
                        (pmax[2] <= mrow[2] + 8.f) && (pmax[3] <= mrow[3] + 8.f);
            if (!__all(keep)) {
#pragma unroll
                for (int r = 0; r < 4; ++r) {
                    float mnew = fmaxf(mrow[r], pmax[r]);
                    float alpha = exp2f(mrow[r] - mnew);
                    mrow[r] = mnew;
                    lrow[r] *= alpha;
#pragma unroll
                    for (int ct = 0; ct < 8; ++ct) O[ct][r] *= alpha;
                }
            }
            float rs[4] = {0.f, 0.f, 0.f, 0.f};
#pragma unroll
            for (int ct = 0; ct < 4; ++ct)
#pragma unroll
                for (int r = 0; r < 4; ++r) {
                    float p = exp2f(sa[ct][r] - mrow[r]);
                    rs[r] += p;
                    // swizzled Ps write: chunk ^= row&7, row = quad*4+r
                    Ps[wave][quad * 4 + r][(ct * 16 + l16) ^ (((quad * 4 + r) & 7) << 3)] = f2h(p);
                }
#pragma unroll
            for (int r = 0; r < 4; ++r) {
#pragma unroll
                for (int off = 1; off < 16; off <<= 1)
                    rs[r] += __shfl_xor(rs[r], off, 64);
                lrow[r] += rs[r];
            }
            __builtin_amdgcn_s_setprio(1);
#pragma unroll
            for (int kc = 0; kc < 2; ++kc) {   // PV from LDS (Ps wave-private)
                f16x8 a = *(const f16x8*)&Ps[wave][l16][(((kc * 4 + quad) ^ sw)) << 3];
#pragma unroll
                for (int ct = 0; ct < 8; ++ct) {
                    f16x8 b = *(const f16x8*)&Vs[ct * 16 + l16][(((kc * 4 + quad) ^ sw)) << 3];
                    O[ct] = __builtin_amdgcn_mfma_f32_16x16x32_f16(a, b, O[ct], 0, 0, 0);
                }
            }
            __builtin_amdgcn_s_setprio(0);

            // ---- commit prefetched tile to LDS (swizzled) ----
            __syncthreads();                   // all waves done reading Ks/Vs
#pragma unroll
            for (int t = 0; t < 4; ++t) {
                int c = tid + t * 256;
                int row = c >> 4, chk = ((c & 15) ^ (row & 7));
                int d = c >> 3, chv = ((c & 7) ^ (d & 7));
                *(u16x8*)&Ks[row][chk << 3] = nk[t];
                *(u16x8*)&Vs[d][chv << 3]   = nv[t];
            }
            __syncthreads();                   // staged data visible
        }
#pragma unroll
        for (int r = 0; r < 4; ++r) {
            float inv = 1.f / lrow[r];
            int row = q0 + wave * 16 + quad * 4 + r;
#pragma unroll
            for (int ct = 0; ct < 8; ++ct)
                AO[(size_t)row * 3584 + h * HD + ct * 16 + l16] = f2h(O[ct][r] * inv);
        }
    }
}

extern "C" void kernel_launch(void* const* d_in, const int* in_sizes, int n_in,
                              void* d_out, int out_size, void* d_ws, size_t ws_size,
                              hipStream_t stream) {
    (void)in_sizes; (void)n_in; (void)out_size;
    const float* hidden = (const float*)d_in[0];
    const int*   pos    = (const int*)d_in[1];
    const int*   qw_q = (const int*)d_in[2];
    const int*   qz_q = (const int*)d_in[3];
    const float* sc_q = (const float*)d_in[4];
    const float* b_q  = (const float*)d_in[5];
    const int*   qw_k = (const int*)d_in[6];
    const int*   qz_k = (const int*)d_in[7];
    const float* sc_k = (const float*)d_in[8];
    const float* b_k  = (const float*)d_in[9];
    const int*   qw_v = (const int*)d_in[10];
    const int*   qz_v = (const int*)d_in[11];
    const float* sc_v = (const float*)d_in[12];
    const float* b_v  = (const float*)d_in[13];
    const int*   qw_o = (const int*)d_in[14];
    const int*   qz_o = (const int*)d_in[15];
    const float* sc_o = (const float*)d_in[16];
    float* out = (float*)d_out;

    char* base = (char*)d_ws;
    size_t off = 0;
    auto alloc = [&](size_t bytes) {
        char* p = base + off;
        off += (bytes + 255) & ~(size_t)255;
        return p;
    };
    u16* Wh = (u16*)alloc((size_t)NQKV * KD * 2);   // 33.0 MB (reused for W_o fallback)
    u16* Xh = (u16*)alloc((size_t)Sq * Hdim * 2);   // 14.7 MB (reused as Qh, then partial)
    u16* Xl = (u16*)alloc((size_t)Sq * Hdim * 2);   // 14.7 MB (Ql, then partial)
    float* Y = (float*)alloc((size_t)Sq * NQKV * 4);// 37.7 MB (reused for AO)
    u16* Khb = (u16*)alloc((size_t)Sq * 512 * 2);   //  2.1 MB
    u16* Vt  = (u16*)alloc((size_t)512 * Sq * 2);   //  2.1 MB
    float* biasc = (float*)alloc(NQKV * 4);
    int*   ctr   = (int*)alloc(4096);               // attn work-queue counter
    // split-K partial for GEMM1 (live GEMM1 -> ropevt); gated on ws_size
    float* Part1 = (float*)alloc((size_t)Sq * NQKV * 4);   // 37.7 MB
    bool deep = (off <= ws_size);
    u16* Wo2 = (u16*)alloc((size_t)3584 * KD * 2);  // 25.7 MB (deq_o target in k_pre)
    bool deep2 = (off <= ws_size);
    u16* Qhb = Xh;                 // Xh dead after GEMM1
    u16* Qlb = Xl;
    u16* AO  = (u16*)Y;            // Y dead after rope/vtrans
    u16* Wo  = Wh;                 // Wh dead after GEMM1 (fallback W_o dst)
    float* Part = (float*)Xh;      // Xh+Xl contiguous = 29.4 MB, dead after attn

    hipMemsetAsync(ctr, 0, 4096, stream);           // ws is re-poisoned each call
    // fused preprocessing: cvt(3584) | bias(18) | deq_q(3136) | deq_k(448)
    //                    | deq_v(448) | deq_o(3136, only if deep2)
    int preBlocks = 3584 + 18 + 3136 + 448 + 448 + (deep2 ? 3136 : 0);
    k_pre<<<preBlocks, 256, 0, stream>>>(hidden, Xh, b_q, b_k, b_v, biasc,
                                         qw_q, qz_q, sc_q, qw_k, qz_k, sc_k,
                                         qw_v, qz_v, sc_v, qw_o, qz_o, sc_o,
                                         Wh, deep2 ? Wo2 : nullptr);
    // GEMM1: 128^2, split-K=2 (1152 blocks = 4.5/CU, best measured: 123us);
    // partial folded into ropevt.
    if (deep) {
        k_gemm_f16<<<dim3(NQKV / 128, Sq / 128, 2), 256, 0, stream>>>(Xh, Wh, biasc, Y, Part1, Sq, NQKV, KD);
    } else {
        k_gemm_f16<<<dim3(NQKV / 128, Sq / 128, 1), 256, 0, stream>>>(Xh, Wh, biasc, Y, nullptr, Sq, NQKV, KD);
    }
    k_ropevt<<<2304, 256, 0, stream>>>(Y, deep ? Part1 : nullptr, pos, Qhb, Qlb, Khb, Vt);
    if (!deep2)   // fallback: dequant W_o into Wh after GEMM1 consumed it
        k_dequant<<<dim3(56, 56), 256, 0, stream>>>(qw_o, qz_o, sc_o, Wo, 3584);
    k_attn<<<dim3(1024), 256, 0, stream>>>(Qhb, Qlb, Khb, Vt, AO, ctr);
    // GEMM2: 256^2 BK=64 coarse counted-vmcnt z=2 (224 blocks, ~111us).
    k_gemm256<<<dim3(Hdim / 256, Sq / 256, 2), 512, 0, stream>>>(AO, deep2 ? Wo2 : Wo, nullptr, out, Part, Sq, Hdim, KD);
    k_reduce<<<(Sq * Hdim / 4 + 255) / 256, 256, 0, stream>>>(out, Part, Sq * Hdim / 4);
}